// Round 19
// baseline (1818.341 us; speedup 1.0000x reference)
//
#include <hip/hip_runtime.h>
#include <math.h>

#define NN 100000
#define NE 300000
#define H 256
#define NT 8
#define NSTEPS 5
#define CHUNK 256
#define NB ((NE + CHUNK - 1) / CHUNK)   // 1172 chunks
#define NBIN ((NN + 127) / 128)         // 782 coarse dst bins
#define MAXBIN 768
#define RS 264                          // LDS row stride in shorts

typedef __attribute__((ext_vector_type(8))) short bf16x8;
typedef __attribute__((ext_vector_type(4))) float f32x4;

static __device__ __forceinline__ short f2bf(float f) {
    union { float f; unsigned u; } v; v.f = f;
    unsigned r = (v.u + 0x7FFFu + ((v.u >> 16) & 1u)) >> 16;
    return (short)r;
}
static __device__ __forceinline__ float bf2f(unsigned short s) {
    union { unsigned u; float f; } v; v.u = ((unsigned)s) << 16;
    return v.f;
}
static __device__ __forceinline__ float fexp2(float x) {
    float r; asm("v_exp_f32 %0, %1" : "=v"(r) : "v"(x)); return r;
}
static __device__ __forceinline__ float frcp(float x) {
    float r; asm("v_rcp_f32 %0, %1" : "=v"(r) : "v"(x)); return r;
}
#define LOG2E 1.442695041f

// ---------------- embedding gather: h0 = emb[x] -> bf16 ----------------
__global__ void k_embed(const int* __restrict__ x, const float* __restrict__ emb,
                        short* __restrict__ h) {
    int total = NN * 32;
    for (int idx = blockIdx.x * blockDim.x + threadIdx.x; idx < total;
         idx += gridDim.x * blockDim.x) {
        int node = idx >> 5;
        int c8 = (idx & 31) * 8;
        const float4* p = reinterpret_cast<const float4*>(
            emb + (size_t)x[node] * H + c8);
        float4 u0 = p[0], u1 = p[1];
        short t[8];
        t[0] = f2bf(u0.x); t[1] = f2bf(u0.y); t[2] = f2bf(u0.z); t[3] = f2bf(u0.w);
        t[4] = f2bf(u1.x); t[5] = f2bf(u1.y); t[6] = f2bf(u1.z); t[7] = f2bf(u1.w);
        *(bf16x8*)(h + (size_t)node * H + c8) = *(bf16x8*)t;
    }
}

// ---------------- weight prep: FRAGMENT-MAJOR bf16 packing ----------------
__global__ void k_prep(const float* __restrict__ wih, const float* __restrict__ whh,
                       const float* __restrict__ Wm,
                       short* __restrict__ wihp, short* __restrict__ whhp,
                       short* __restrict__ Wmp) {
    const int NW = 3 * H * H;
    const int NM = NT * H * H;
    for (int i = blockIdx.x * blockDim.x + threadIdx.x; i < 2 * NW + NM;
         i += gridDim.x * blockDim.x) {
        if (i < 2 * NW) {
            int which = (i >= NW);
            int j = which ? i - NW : i;
            int m = j & 7, lane = (j >> 3) & 63;
            int cc = (j >> 9) & 15, kk = (j >> 13) & 7, gate = j >> 16;
            int row = gate * H + cc * 16 + (lane & 15);
            int col = kk * 32 + (lane >> 4) * 8 + m;
            const float* src = which ? whh : wih;
            (which ? whhp : wihp)[j] = f2bf(src[(size_t)row * H + col]);
        } else {
            int j = i - 2 * NW;
            int m = j & 7, lane = (j >> 3) & 63;
            int cc = (j >> 9) & 15, kk = (j >> 13) & 7, t = j >> 16;
            int jcol = cc * 16 + (lane & 15);
            int krow = kk * 32 + (lane >> 4) * 8 + m;
            Wmp[j] = f2bf(Wm[(size_t)t * H * H + (size_t)krow * H + jcol]);
        }
    }
}

// ---------------- stable counting sort of edges by TYPE ----------
__global__ void k_hist(const int* __restrict__ etype, int* __restrict__ hist_tb) {
    __shared__ int lh[NT];
    int b = blockIdx.x;
    if (threadIdx.x < NT) lh[threadIdx.x] = 0;
    __syncthreads();
    int e = b * CHUNK + threadIdx.x;
    if (e < NE) atomicAdd(&lh[etype[e]], 1);
    __syncthreads();
    if (threadIdx.x < NT) hist_tb[threadIdx.x * NB + b] = lh[threadIdx.x];
}

__global__ void k_scan(const int* __restrict__ hist_tb, int* __restrict__ off_tb,
                       int* __restrict__ pstart, int* __restrict__ perm) {
    __shared__ int total[NT];
    int t = threadIdx.x;
    if (t < NT) {
        int run = 0;
        for (int b = 0; b < NB; b++) {
            off_tb[t * NB + b] = run;
            run += hist_tb[t * NB + b];
        }
        total[t] = run;
    }
    __syncthreads();
    if (t == 0) {
        int p = 0;
        for (int tt = 0; tt < NT; tt++) {
            pstart[tt] = p;
            int padded = (total[tt] + 127) / 128 * 128;
            for (int q = total[tt]; q < padded; q++) perm[p + q] = -1;
            p += padded;
        }
        pstart[NT] = p;
    }
}

__global__ void k_scatter(const int* __restrict__ etype, const int* __restrict__ off_tb,
                          const int* __restrict__ pstart, int* __restrict__ perm) {
    __shared__ int st[CHUNK];
    int b = blockIdx.x;
    int e = b * CHUNK + threadIdx.x;
    st[threadIdx.x] = (e < NE) ? etype[e] : -1;
    __syncthreads();
    if (e < NE) {
        int t = st[threadIdx.x];
        int r = 0;
        for (int i = 0; i < threadIdx.x; i++) r += (st[i] == t);
        perm[pstart[t] + off_tb[t * NB + b] + r] = e;
    }
}

// ---------------- stable counting sort of edges by DST ----
__global__ void k_hist2(const int* __restrict__ ei, int* __restrict__ hist2) {
    __shared__ int lh[NBIN];
    int b = blockIdx.x;
    for (int i = threadIdx.x; i < NBIN; i += 256) lh[i] = 0;
    __syncthreads();
    int e = b * CHUNK + threadIdx.x;
    if (e < NE) atomicAdd(&lh[ei[NE + e] >> 7], 1);
    __syncthreads();
    for (int i = threadIdx.x; i < NBIN; i += 256) hist2[i * NB + b] = lh[i];
}

__global__ void k_scan2a(const int* __restrict__ hist2, int* __restrict__ off2,
                         int* __restrict__ bintot) {
    int t = blockIdx.x * 256 + threadIdx.x;
    if (t >= NBIN) return;
    int run = 0;
    for (int c = 0; c < NB; c++) {
        off2[t * NB + c] = run;
        run += hist2[t * NB + c];
    }
    bintot[t] = run;
}

__global__ void k_scan2b(const int* __restrict__ bintot, int* __restrict__ binstart,
                         int* __restrict__ csr) {
    int p = 0;
    for (int b = 0; b < NBIN; b++) { binstart[b] = p; p += bintot[b]; }
    binstart[NBIN] = p;
    csr[NN] = NE;
}

__global__ void k_scatter2(const int* __restrict__ ei, const int* __restrict__ off2,
                           const int* __restrict__ binstart, int* __restrict__ ebin) {
    __shared__ short sb[CHUNK];
    int b = blockIdx.x;
    int e = b * CHUNK + threadIdx.x;
    int bin = (e < NE) ? (ei[NE + e] >> 7) : -1;
    sb[threadIdx.x] = (short)bin;
    __syncthreads();
    if (e < NE) {
        int r = 0;
        for (int i = 0; i < threadIdx.x; i++) r += (sb[i] == (short)bin);
        ebin[binstart[bin] + off2[bin * NB + b] + r] = e;
    }
}

__global__ __launch_bounds__(256) void k_lsort(
    const int* __restrict__ ei, const int* __restrict__ binstart,
    const int* __restrict__ ebin, int* __restrict__ csr, int* __restrict__ pos) {
    int b = blockIdx.x;
    int beg = binstart[b], cnt = binstart[b + 1] - beg;
    __shared__ unsigned short ld[MAXBIN];
    __shared__ int lh[128], ls[128];
    for (int i = threadIdx.x; i < 128; i += 256) lh[i] = 0;
    __syncthreads();
    for (int i = threadIdx.x; i < cnt; i += 256) {
        int d = ei[NE + ebin[beg + i]] & 127;
        ld[i] = (unsigned short)d;
        atomicAdd(&lh[d], 1);
    }
    __syncthreads();
    if (threadIdx.x == 0) {
        int run = 0;
        for (int l = 0; l < 128; l++) { ls[l] = run; run += lh[l]; }
    }
    __syncthreads();
    int base = b * 128;
    for (int l = threadIdx.x; l < 128; l += 256) {
        int dst = base + l;
        if (dst < NN) csr[dst] = beg + ls[l];
    }
    for (int i = threadIdx.x; i < cnt; i += 256) {
        int d = ld[i], r = 0;
        for (int j = 0; j < i; j++) r += (ld[j] == d);
        pos[ebin[beg + i]] = beg + ls[d] + r;
    }
}

// ---------------- message GEMM (MFMA): msg[pos[e]] = h[src] @ W[t] + b[t] ----
// Unchanged (round-13 structure).
__global__ __launch_bounds__(512) void k_msg(
    const int* __restrict__ perm, const int* __restrict__ pstart,
    const int* __restrict__ ei, const short* __restrict__ hcurb,
    const short* __restrict__ Wmp, const float* __restrict__ bm,
    const int* __restrict__ pos, short* __restrict__ msg) {
    int Epad = pstart[NT];
    int e0 = blockIdx.x * 128;
    if (e0 >= Epad) return;
    int t = 0;
    while (t < NT - 1 && e0 >= pstart[t + 1]) t++;

    __shared__ short sA[128][RS];
    __shared__ int se[128], pe[128];

    int tid = threadIdx.x;
    if (tid < 128) {
        int eid = perm[e0 + tid];
        se[tid] = (eid >= 0) ? ei[eid] : -1;
        pe[tid] = (eid >= 0) ? pos[eid] : -1;
    }
    __syncthreads();

    for (int task = tid; task < 1024; task += 512) {
        int r = task >> 3, c0 = (task & 7) * 32;
        int s = se[r];
        if (s >= 0) {
            const short* p = hcurb + (size_t)s * H + c0;
#pragma unroll
            for (int i = 0; i < 4; i++)
                *(bf16x8*)&sA[r][c0 + i * 8] = *(const bf16x8*)(p + i * 8);
        } else {
            bf16x8 z = {};
#pragma unroll
            for (int i = 0; i < 4; i++) *(bf16x8*)&sA[r][c0 + i * 8] = z;
        }
    }
    __syncthreads();

    int wid = tid >> 6, lane = tid & 63;
    int jw = wid * 32;
    int lr = lane & 15, lg = lane >> 4;

    f32x4 acc[8][2] = {};

    for (int kk = 0; kk < 8; kk++) {
        const short* fp = Wmp + (((size_t)(t * 8 + kk) * 16 + wid * 2) << 9) + lane * 8;
        bf16x8 fb[2];
        fb[0] = *(const bf16x8*)fp;
        fb[1] = *(const bf16x8*)(fp + 512);
        int k0 = kk * 32;
#pragma unroll
        for (int rh = 0; rh < 8; rh++) {
            bf16x8 fa = *(const bf16x8*)&sA[rh * 16 + lr][k0 + lg * 8];
#pragma unroll
            for (int ch = 0; ch < 2; ch++)
                acc[rh][ch] = __builtin_amdgcn_mfma_f32_16x16x32_bf16(
                    fa, fb[ch], acc[rh][ch], 0, 0, 0);
        }
    }

    __syncthreads();
    float bmv[2];
#pragma unroll
    for (int ch = 0; ch < 2; ch++) bmv[ch] = bm[t * H + jw + ch * 16 + lr];
#pragma unroll
    for (int rh = 0; rh < 8; rh++) {
#pragma unroll
        for (int reg = 0; reg < 4; reg++) {
            int row = rh * 16 + lg * 4 + reg;
#pragma unroll
            for (int ch = 0; ch < 2; ch++)
                sA[row][jw + ch * 16 + lr] = f2bf(acc[rh][ch][reg] + bmv[ch]);
        }
    }
    __syncthreads();
    for (int task = tid; task < 1024; task += 512) {
        int r = task >> 3, c0 = (task & 7) * 32;
        int p = pe[r];
        if (p < 0) continue;
        short* dstp = msg + (size_t)p * H + c0;
#pragma unroll
        for (int i = 0; i < 4; i++)
            *(bf16x8*)(dstp + i * 8) = *(bf16x8*)&sA[r][c0 + i * 8];
    }
}

// ---------------- fused segment-sum + GRU (round-19) ------------------------
// Round-18 champion (32x256 tile, acc 64 f32, ~41% occ) + staged bf16
// epilogue store: vals computed to regs (reads sH), then sA (dead after MFMA)
// is overwritten with bf16 results and stored as coalesced 64B/thread rows.
// Removes the 2x write amplification (WRITE 100->50 MB) that round-15 proved
// fixable; now amortized over 4 resident blocks/CU instead of 1.
__global__ __launch_bounds__(512) void k_gru(
    const short* __restrict__ msg, const int* __restrict__ csr,
    const short* __restrict__ hcurb, short* __restrict__ hnextb,
    float* __restrict__ outf,
    const short* __restrict__ wihp, const short* __restrict__ whhp,
    const float* __restrict__ bih, const float* __restrict__ bhh) {
    int n0 = blockIdx.x * 32;
    int tid = threadIdx.x;

    __shared__ short sA[32][RS];
    __shared__ short sH[32][RS];

    // staging: 512 tasks = 2 mats x 32 rows x 8 col-chunks(32); 1 per thread
    {
        int which = tid >> 8;           // 0: seg-sum msg->sA, 1: copy h->sH
        int t2 = tid & 255;
        int r = t2 >> 3, c0 = (t2 & 7) * 32;
        int n = n0 + r;
        if (which == 0) {
            float a[32];
#pragma unroll
            for (int i = 0; i < 32; i++) a[i] = 0.f;
            if (n < NN) {
                int beg = csr[n], end = csr[n + 1];
                for (int s = beg; s < end; s++) {
                    const short* mp = msg + (size_t)s * H + c0;
#pragma unroll
                    for (int i = 0; i < 4; i++) {
                        bf16x8 v = *(const bf16x8*)(mp + i * 8);
#pragma unroll
                        for (int m = 0; m < 8; m++)
                            a[i * 8 + m] += bf2f((unsigned short)v[m]);
                    }
                }
            }
            short tmp[32];
#pragma unroll
            for (int i = 0; i < 32; i++) tmp[i] = f2bf(a[i]);
#pragma unroll
            for (int i = 0; i < 4; i++)
                *(bf16x8*)&sA[r][c0 + i * 8] = *(bf16x8*)&tmp[i * 8];
        } else {
            if (n < NN) {
                const short* p = hcurb + (size_t)n * H + c0;
#pragma unroll
                for (int i = 0; i < 4; i++)
                    *(bf16x8*)&sH[r][c0 + i * 8] = *(const bf16x8*)(p + i * 8);
            } else {
                bf16x8 z = {};
#pragma unroll
                for (int i = 0; i < 4; i++) *(bf16x8*)&sH[r][c0 + i * 8] = z;
            }
        }
    }
    __syncthreads();

    int wid = tid >> 6, lane = tid & 63;
    int jw = wid * 32;
    int lr = lane & 15, lg = lane >> 4;

    // acc[0]=r (i_r+h_r), acc[1]=z (i_z+h_z), acc[2]=i_n, acc[3]=h_n
    f32x4 acc[4][2][2] = {};

    for (int kk = 0; kk < 8; kk++) {
        int k0 = kk * 32;
        bf16x8 fa[2], fh[2];
#pragma unroll
        for (int rh = 0; rh < 2; rh++) {
            fa[rh] = *(const bf16x8*)&sA[rh * 16 + lr][k0 + lg * 8];
            fh[rh] = *(const bf16x8*)&sH[rh * 16 + lr][k0 + lg * 8];
        }
        // g: 0=ih_r 1=hh_r 2=ih_z 3=hh_z 4=ih_n 5=hh_n
#pragma unroll
        for (int g = 0; g < 6; g++) {
            const short* wp = (g & 1) ? whhp : wihp;
            int gate = g >> 1;
            int di = (g < 4) ? (g >> 1) : (g - 2);   // 0,0,1,1,2,3
            const short* fp = wp + (((size_t)(gate * 8 + kk) * 16 + wid * 2) << 9) + lane * 8;
            bf16x8 fb[2];
            fb[0] = *(const bf16x8*)fp;
            fb[1] = *(const bf16x8*)(fp + 512);
#pragma unroll
            for (int rh = 0; rh < 2; rh++)
#pragma unroll
                for (int ch = 0; ch < 2; ch++)
                    acc[di][rh][ch] = __builtin_amdgcn_mfma_f32_16x16x32_bf16(
                        (g & 1) ? fh[rh] : fa[rh], fb[ch], acc[di][rh][ch], 0, 0, 0);
        }
    }

    float b_r[2], b_z[2], b_in[2], b_hn[2];
#pragma unroll
    for (int ch = 0; ch < 2; ch++) {
        int jj = jw + ch * 16 + lr;
        b_r[ch]  = bih[jj] + bhh[jj];
        b_z[ch]  = bih[H + jj] + bhh[H + jj];
        b_in[ch] = bih[2 * H + jj];
        b_hn[ch] = bhh[2 * H + jj];
    }
    float vals[16];
#pragma unroll
    for (int rh = 0; rh < 2; rh++) {
#pragma unroll
        for (int reg = 0; reg < 4; reg++) {
            int row = rh * 16 + lg * 4 + reg;
#pragma unroll
            for (int ch = 0; ch < 2; ch++) {
                int jj = jw + ch * 16 + lr;
                float rr = acc[0][rh][ch][reg] + b_r[ch];
                float zz = acc[1][rh][ch][reg] + b_z[ch];
                float nn = acc[2][rh][ch][reg] + b_in[ch];
                float hn = acc[3][rh][ch][reg] + b_hn[ch];
                float r = frcp(1.f + fexp2(rr * -LOG2E));
                float z = frcp(1.f + fexp2(zz * -LOG2E));
                float x = nn + r * hn;
                float nv = 2.f * frcp(1.f + fexp2(x * -2.f * LOG2E)) - 1.f;
                float ho = bf2f((unsigned short)sH[row][jj]);
                vals[(rh * 4 + reg) * 2 + ch] = (1.f - z) * nv + z * ho;
            }
        }
    }
    if (outf) {
        // fp32 final output: 16-lane groups write 64B contiguous
#pragma unroll
        for (int rh = 0; rh < 2; rh++)
#pragma unroll
            for (int reg = 0; reg < 4; reg++) {
                int n = n0 + rh * 16 + lg * 4 + reg;
                if (n >= NN) continue;
#pragma unroll
                for (int ch = 0; ch < 2; ch++)
                    outf[(size_t)n * H + jw + ch * 16 + lr] =
                        vals[(rh * 4 + reg) * 2 + ch];
            }
    } else {
        // bf16 mid-step: stage through sA (dead), coalesced 64B/thread stores
        __syncthreads();
#pragma unroll
        for (int rh = 0; rh < 2; rh++)
#pragma unroll
            for (int reg = 0; reg < 4; reg++) {
                int row = rh * 16 + lg * 4 + reg;
#pragma unroll
                for (int ch = 0; ch < 2; ch++)
                    sA[row][jw + ch * 16 + lr] =
                        f2bf(vals[(rh * 4 + reg) * 2 + ch]);
            }
        __syncthreads();
        if (tid < 256) {
            int r = tid >> 3, c0 = (tid & 7) * 32;
            int n = n0 + r;
            if (n < NN) {
                short* dstp = hnextb + (size_t)n * H + c0;
#pragma unroll
                for (int i = 0; i < 4; i++)
                    *(bf16x8*)(dstp + i * 8) = *(bf16x8*)&sA[r][c0 + i * 8];
            }
        }
    }
}

extern "C" void kernel_launch(void* const* d_in, const int* in_sizes, int n_in,
                              void* d_out, int out_size, void* d_ws, size_t ws_size,
                              hipStream_t stream) {
    const int*   x     = (const int*)d_in[0];
    const int*   ei    = (const int*)d_in[1];
    const int*   etype = (const int*)d_in[2];
    const float* emb   = (const float*)d_in[3];
    const float* Wm    = (const float*)d_in[4];
    const float* bm    = (const float*)d_in[5];
    const float* wih   = (const float*)d_in[6];
    const float* whh   = (const float*)d_in[7];
    const float* bih   = (const float*)d_in[8];
    const float* bhh   = (const float*)d_in[9];

    float* out = (float*)d_out;

    // workspace layout
    short* hA    = (short*)d_ws;                         // [NN,H] bf16
    short* hB    = hA + (size_t)NN * H;                  // [NN,H] bf16
    short* wihp  = hB + (size_t)NN * H;                  // packed [3][8][16][64][8]
    short* whhp  = wihp + 3 * H * H;
    short* Wmp   = whhp + 3 * H * H;                     // packed [NT][8][16][64][8]
    short* msg   = Wmp + NT * H * H;                     // [NE,H] bf16
    int* hist_tb = (int*)(msg + (size_t)NE * H);         // [NT,NB]
    int* off_tb  = hist_tb + NT * NB;
    int* pstart  = off_tb + NT * NB;                     // [NT+1]
    int* perm    = pstart + 16;                          // [NE + NT*128]
    int* hist2   = perm + NE + NT * 128;                 // [NBIN,NB]
    int* off2    = hist2 + NBIN * NB;                    // [NBIN,NB]
    int* bintot  = off2 + NBIN * NB;                     // [NBIN]
    int* binstart= bintot + NBIN;                        // [NBIN+1]
    int* ebin    = binstart + NBIN + 1;                  // [NE]
    int* pos     = ebin + NE;                            // [NE]
    int* csr     = pos + NE;                             // [NN+1]

    k_embed<<<2048, 256, 0, stream>>>(x, emb, hA);
    k_prep<<<720, 256, 0, stream>>>(wih, whh, Wm, wihp, whhp, Wmp);

    // one-time: type sort (GEMM order)
    k_hist<<<NB, CHUNK, 0, stream>>>(etype, hist_tb);
    k_scan<<<1, 64, 0, stream>>>(hist_tb, off_tb, pstart, perm);
    k_scatter<<<NB, CHUNK, 0, stream>>>(etype, off_tb, pstart, perm);

    // one-time: dst sort (segment-sum order) -> pos[], csr[]
    k_hist2<<<NB, CHUNK, 0, stream>>>(ei, hist2);
    k_scan2a<<<(NBIN + 255) / 256, 256, 0, stream>>>(hist2, off2, bintot);
    k_scan2b<<<1, 1, 0, stream>>>(bintot, binstart, csr);
    k_scatter2<<<NB, CHUNK, 0, stream>>>(ei, off2, binstart, ebin);
    k_lsort<<<NBIN, 256, 0, stream>>>(ei, binstart, ebin, csr, pos);

    const int MSG_BX = (NE + NT * 128 + 127) / 128;
    const int GRU_BX = (NN + 31) / 32;     // 3125

    short* hcur = hA;
    short* hnxt = hB;
    for (int s = 0; s < NSTEPS; s++) {
        int last = (s == NSTEPS - 1);
        k_msg<<<MSG_BX, 512, 0, stream>>>(perm, pstart, ei, hcur, Wmp, bm, pos, msg);
        k_gru<<<GRU_BX, 512, 0, stream>>>(msg, csr, hcur, hnxt,
                                          last ? out : nullptr,
                                          wihp, whhp, bih, bhh);
        short* tmp = hcur; hcur = hnxt; hnxt = tmp;
    }
}

// Round 20
// 1531.187 us; speedup vs baseline: 1.1875x; 1.1875x over previous
//
#include <hip/hip_runtime.h>
#include <math.h>

#define NN 100000
#define NE 300000
#define H 256
#define NT 8
#define NSTEPS 5
#define CHUNK 256
#define NB ((NE + CHUNK - 1) / CHUNK)   // 1172 chunks
#define NBIN ((NN + 127) / 128)         // 782 coarse dst bins
#define MAXBIN 768
#define RS 264                          // LDS row stride in shorts

typedef __attribute__((ext_vector_type(8))) short bf16x8;
typedef __attribute__((ext_vector_type(4))) float f32x4;

static __device__ __forceinline__ short f2bf(float f) {
    union { float f; unsigned u; } v; v.f = f;
    unsigned r = (v.u + 0x7FFFu + ((v.u >> 16) & 1u)) >> 16;
    return (short)r;
}
static __device__ __forceinline__ float bf2f(unsigned short s) {
    union { unsigned u; float f; } v; v.u = ((unsigned)s) << 16;
    return v.f;
}
static __device__ __forceinline__ float fexp2(float x) {
    float r; asm("v_exp_f32 %0, %1" : "=v"(r) : "v"(x)); return r;
}
static __device__ __forceinline__ float frcp(float x) {
    float r; asm("v_rcp_f32 %0, %1" : "=v"(r) : "v"(x)); return r;
}
#define LOG2E 1.442695041f

// ---------------- embedding gather: h0 = emb[x] -> bf16 ----------------
__global__ void k_embed(const int* __restrict__ x, const float* __restrict__ emb,
                        short* __restrict__ h) {
    int total = NN * 32;
    for (int idx = blockIdx.x * blockDim.x + threadIdx.x; idx < total;
         idx += gridDim.x * blockDim.x) {
        int node = idx >> 5;
        int c8 = (idx & 31) * 8;
        const float4* p = reinterpret_cast<const float4*>(
            emb + (size_t)x[node] * H + c8);
        float4 u0 = p[0], u1 = p[1];
        short t[8];
        t[0] = f2bf(u0.x); t[1] = f2bf(u0.y); t[2] = f2bf(u0.z); t[3] = f2bf(u0.w);
        t[4] = f2bf(u1.x); t[5] = f2bf(u1.y); t[6] = f2bf(u1.z); t[7] = f2bf(u1.w);
        *(bf16x8*)(h + (size_t)node * H + c8) = *(bf16x8*)t;
    }
}

// ---------------- weight prep: FRAGMENT-MAJOR bf16 packing ----------------
__global__ void k_prep(const float* __restrict__ wih, const float* __restrict__ whh,
                       const float* __restrict__ Wm,
                       short* __restrict__ wihp, short* __restrict__ whhp,
                       short* __restrict__ Wmp) {
    const int NW = 3 * H * H;
    const int NM = NT * H * H;
    for (int i = blockIdx.x * blockDim.x + threadIdx.x; i < 2 * NW + NM;
         i += gridDim.x * blockDim.x) {
        if (i < 2 * NW) {
            int which = (i >= NW);
            int j = which ? i - NW : i;
            int m = j & 7, lane = (j >> 3) & 63;
            int cc = (j >> 9) & 15, kk = (j >> 13) & 7, gate = j >> 16;
            int row = gate * H + cc * 16 + (lane & 15);
            int col = kk * 32 + (lane >> 4) * 8 + m;
            const float* src = which ? whh : wih;
            (which ? whhp : wihp)[j] = f2bf(src[(size_t)row * H + col]);
        } else {
            int j = i - 2 * NW;
            int m = j & 7, lane = (j >> 3) & 63;
            int cc = (j >> 9) & 15, kk = (j >> 13) & 7, t = j >> 16;
            int jcol = cc * 16 + (lane & 15);
            int krow = kk * 32 + (lane >> 4) * 8 + m;
            Wmp[j] = f2bf(Wm[(size_t)t * H * H + (size_t)krow * H + jcol]);
        }
    }
}

// ---------------- stable counting sort of edges by TYPE ----------
__global__ void k_hist(const int* __restrict__ etype, int* __restrict__ hist_tb) {
    __shared__ int lh[NT];
    int b = blockIdx.x;
    if (threadIdx.x < NT) lh[threadIdx.x] = 0;
    __syncthreads();
    int e = b * CHUNK + threadIdx.x;
    if (e < NE) atomicAdd(&lh[etype[e]], 1);
    __syncthreads();
    if (threadIdx.x < NT) hist_tb[threadIdx.x * NB + b] = lh[threadIdx.x];
}

__global__ void k_scan(const int* __restrict__ hist_tb, int* __restrict__ off_tb,
                       int* __restrict__ pstart, int* __restrict__ perm) {
    __shared__ int total[NT];
    int t = threadIdx.x;
    if (t < NT) {
        int run = 0;
        for (int b = 0; b < NB; b++) {
            off_tb[t * NB + b] = run;
            run += hist_tb[t * NB + b];
        }
        total[t] = run;
    }
    __syncthreads();
    if (t == 0) {
        int p = 0;
        for (int tt = 0; tt < NT; tt++) {
            pstart[tt] = p;
            int padded = (total[tt] + 127) / 128 * 128;
            for (int q = total[tt]; q < padded; q++) perm[p + q] = -1;
            p += padded;
        }
        pstart[NT] = p;
    }
}

__global__ void k_scatter(const int* __restrict__ etype, const int* __restrict__ off_tb,
                          const int* __restrict__ pstart, int* __restrict__ perm) {
    __shared__ int st[CHUNK];
    int b = blockIdx.x;
    int e = b * CHUNK + threadIdx.x;
    st[threadIdx.x] = (e < NE) ? etype[e] : -1;
    __syncthreads();
    if (e < NE) {
        int t = st[threadIdx.x];
        int r = 0;
        for (int i = 0; i < threadIdx.x; i++) r += (st[i] == t);
        perm[pstart[t] + off_tb[t * NB + b] + r] = e;
    }
}

// ---------------- stable counting sort of edges by DST ----
__global__ void k_hist2(const int* __restrict__ ei, int* __restrict__ hist2) {
    __shared__ int lh[NBIN];
    int b = blockIdx.x;
    for (int i = threadIdx.x; i < NBIN; i += 256) lh[i] = 0;
    __syncthreads();
    int e = b * CHUNK + threadIdx.x;
    if (e < NE) atomicAdd(&lh[ei[NE + e] >> 7], 1);
    __syncthreads();
    for (int i = threadIdx.x; i < NBIN; i += 256) hist2[i * NB + b] = lh[i];
}

__global__ void k_scan2a(const int* __restrict__ hist2, int* __restrict__ off2,
                         int* __restrict__ bintot) {
    int t = blockIdx.x * 256 + threadIdx.x;
    if (t >= NBIN) return;
    int run = 0;
    for (int c = 0; c < NB; c++) {
        off2[t * NB + c] = run;
        run += hist2[t * NB + c];
    }
    bintot[t] = run;
}

__global__ void k_scan2b(const int* __restrict__ bintot, int* __restrict__ binstart,
                         int* __restrict__ csr) {
    int p = 0;
    for (int b = 0; b < NBIN; b++) { binstart[b] = p; p += bintot[b]; }
    binstart[NBIN] = p;
    csr[NN] = NE;
}

__global__ void k_scatter2(const int* __restrict__ ei, const int* __restrict__ off2,
                           const int* __restrict__ binstart, int* __restrict__ ebin) {
    __shared__ short sb[CHUNK];
    int b = blockIdx.x;
    int e = b * CHUNK + threadIdx.x;
    int bin = (e < NE) ? (ei[NE + e] >> 7) : -1;
    sb[threadIdx.x] = (short)bin;
    __syncthreads();
    if (e < NE) {
        int r = 0;
        for (int i = 0; i < threadIdx.x; i++) r += (sb[i] == (short)bin);
        ebin[binstart[bin] + off2[bin * NB + b] + r] = e;
    }
}

__global__ __launch_bounds__(256) void k_lsort(
    const int* __restrict__ ei, const int* __restrict__ binstart,
    const int* __restrict__ ebin, int* __restrict__ csr, int* __restrict__ pos) {
    int b = blockIdx.x;
    int beg = binstart[b], cnt = binstart[b + 1] - beg;
    __shared__ unsigned short ld[MAXBIN];
    __shared__ int lh[128], ls[128];
    for (int i = threadIdx.x; i < 128; i += 256) lh[i] = 0;
    __syncthreads();
    for (int i = threadIdx.x; i < cnt; i += 256) {
        int d = ei[NE + ebin[beg + i]] & 127;
        ld[i] = (unsigned short)d;
        atomicAdd(&lh[d], 1);
    }
    __syncthreads();
    if (threadIdx.x == 0) {
        int run = 0;
        for (int l = 0; l < 128; l++) { ls[l] = run; run += lh[l]; }
    }
    __syncthreads();
    int base = b * 128;
    for (int l = threadIdx.x; l < 128; l += 256) {
        int dst = base + l;
        if (dst < NN) csr[dst] = beg + ls[l];
    }
    for (int i = threadIdx.x; i < cnt; i += 256) {
        int d = ld[i], r = 0;
        for (int j = 0; j < i; j++) r += (ld[j] == d);
        pos[ebin[beg + i]] = beg + ls[d] + r;
    }
}

// ---------------- message GEMM (MFMA): msg[pos[e]] = h[src] @ W[t] + b[t] ----
// Round-13 structure (measured best).
__global__ __launch_bounds__(512) void k_msg(
    const int* __restrict__ perm, const int* __restrict__ pstart,
    const int* __restrict__ ei, const short* __restrict__ hcurb,
    const short* __restrict__ Wmp, const float* __restrict__ bm,
    const int* __restrict__ pos, short* __restrict__ msg) {
    int Epad = pstart[NT];
    int e0 = blockIdx.x * 128;
    if (e0 >= Epad) return;
    int t = 0;
    while (t < NT - 1 && e0 >= pstart[t + 1]) t++;

    __shared__ short sA[128][RS];
    __shared__ int se[128], pe[128];

    int tid = threadIdx.x;
    if (tid < 128) {
        int eid = perm[e0 + tid];
        se[tid] = (eid >= 0) ? ei[eid] : -1;
        pe[tid] = (eid >= 0) ? pos[eid] : -1;
    }
    __syncthreads();

    for (int task = tid; task < 1024; task += 512) {
        int r = task >> 3, c0 = (task & 7) * 32;
        int s = se[r];
        if (s >= 0) {
            const short* p = hcurb + (size_t)s * H + c0;
#pragma unroll
            for (int i = 0; i < 4; i++)
                *(bf16x8*)&sA[r][c0 + i * 8] = *(const bf16x8*)(p + i * 8);
        } else {
            bf16x8 z = {};
#pragma unroll
            for (int i = 0; i < 4; i++) *(bf16x8*)&sA[r][c0 + i * 8] = z;
        }
    }
    __syncthreads();

    int wid = tid >> 6, lane = tid & 63;
    int jw = wid * 32;
    int lr = lane & 15, lg = lane >> 4;

    f32x4 acc[8][2] = {};

    for (int kk = 0; kk < 8; kk++) {
        const short* fp = Wmp + (((size_t)(t * 8 + kk) * 16 + wid * 2) << 9) + lane * 8;
        bf16x8 fb[2];
        fb[0] = *(const bf16x8*)fp;
        fb[1] = *(const bf16x8*)(fp + 512);
        int k0 = kk * 32;
#pragma unroll
        for (int rh = 0; rh < 8; rh++) {
            bf16x8 fa = *(const bf16x8*)&sA[rh * 16 + lr][k0 + lg * 8];
#pragma unroll
            for (int ch = 0; ch < 2; ch++)
                acc[rh][ch] = __builtin_amdgcn_mfma_f32_16x16x32_bf16(
                    fa, fb[ch], acc[rh][ch], 0, 0, 0);
        }
    }

    __syncthreads();
    float bmv[2];
#pragma unroll
    for (int ch = 0; ch < 2; ch++) bmv[ch] = bm[t * H + jw + ch * 16 + lr];
#pragma unroll
    for (int rh = 0; rh < 8; rh++) {
#pragma unroll
        for (int reg = 0; reg < 4; reg++) {
            int row = rh * 16 + lg * 4 + reg;
#pragma unroll
            for (int ch = 0; ch < 2; ch++)
                sA[row][jw + ch * 16 + lr] = f2bf(acc[rh][ch][reg] + bmv[ch]);
        }
    }
    __syncthreads();
    for (int task = tid; task < 1024; task += 512) {
        int r = task >> 3, c0 = (task & 7) * 32;
        int p = pe[r];
        if (p < 0) continue;
        short* dstp = msg + (size_t)p * H + c0;
#pragma unroll
        for (int i = 0; i < 4; i++)
            *(bf16x8*)(dstp + i * 8) = *(bf16x8*)&sA[r][c0 + i * 8];
    }
}

// ---------------- fused segment-sum + GRU (round-18 champion) ---------------
// 32x256 tile, 512 thr (8 waves x 32-col slice), staging once per 32 rows,
// per-wave acc [4][2][2]=64 f32 -> VGPR 64 -> ~41% occupancy. Direct stores
// (rounds 15+19 proved staged stores regress despite halved WRITE_SIZE).
__global__ __launch_bounds__(512) void k_gru(
    const short* __restrict__ msg, const int* __restrict__ csr,
    const short* __restrict__ hcurb, short* __restrict__ hnextb,
    float* __restrict__ outf,
    const short* __restrict__ wihp, const short* __restrict__ whhp,
    const float* __restrict__ bih, const float* __restrict__ bhh) {
    int n0 = blockIdx.x * 32;
    int tid = threadIdx.x;

    __shared__ short sA[32][RS];
    __shared__ short sH[32][RS];

    // staging: 512 tasks = 2 mats x 32 rows x 8 col-chunks(32); 1 per thread
    {
        int which = tid >> 8;           // 0: seg-sum msg->sA, 1: copy h->sH
        int t2 = tid & 255;
        int r = t2 >> 3, c0 = (t2 & 7) * 32;
        int n = n0 + r;
        if (which == 0) {
            float a[32];
#pragma unroll
            for (int i = 0; i < 32; i++) a[i] = 0.f;
            if (n < NN) {
                int beg = csr[n], end = csr[n + 1];
                for (int s = beg; s < end; s++) {
                    const short* mp = msg + (size_t)s * H + c0;
#pragma unroll
                    for (int i = 0; i < 4; i++) {
                        bf16x8 v = *(const bf16x8*)(mp + i * 8);
#pragma unroll
                        for (int m = 0; m < 8; m++)
                            a[i * 8 + m] += bf2f((unsigned short)v[m]);
                    }
                }
            }
            short tmp[32];
#pragma unroll
            for (int i = 0; i < 32; i++) tmp[i] = f2bf(a[i]);
#pragma unroll
            for (int i = 0; i < 4; i++)
                *(bf16x8*)&sA[r][c0 + i * 8] = *(bf16x8*)&tmp[i * 8];
        } else {
            if (n < NN) {
                const short* p = hcurb + (size_t)n * H + c0;
#pragma unroll
                for (int i = 0; i < 4; i++)
                    *(bf16x8*)&sH[r][c0 + i * 8] = *(const bf16x8*)(p + i * 8);
            } else {
                bf16x8 z = {};
#pragma unroll
                for (int i = 0; i < 4; i++) *(bf16x8*)&sH[r][c0 + i * 8] = z;
            }
        }
    }
    __syncthreads();

    int wid = tid >> 6, lane = tid & 63;
    int jw = wid * 32;
    int lr = lane & 15, lg = lane >> 4;

    // acc[0]=r (i_r+h_r), acc[1]=z (i_z+h_z), acc[2]=i_n, acc[3]=h_n
    f32x4 acc[4][2][2] = {};

    for (int kk = 0; kk < 8; kk++) {
        int k0 = kk * 32;
        bf16x8 fa[2], fh[2];
#pragma unroll
        for (int rh = 0; rh < 2; rh++) {
            fa[rh] = *(const bf16x8*)&sA[rh * 16 + lr][k0 + lg * 8];
            fh[rh] = *(const bf16x8*)&sH[rh * 16 + lr][k0 + lg * 8];
        }
        // g: 0=ih_r 1=hh_r 2=ih_z 3=hh_z 4=ih_n 5=hh_n
#pragma unroll
        for (int g = 0; g < 6; g++) {
            const short* wp = (g & 1) ? whhp : wihp;
            int gate = g >> 1;
            int di = (g < 4) ? (g >> 1) : (g - 2);   // 0,0,1,1,2,3
            const short* fp = wp + (((size_t)(gate * 8 + kk) * 16 + wid * 2) << 9) + lane * 8;
            bf16x8 fb[2];
            fb[0] = *(const bf16x8*)fp;
            fb[1] = *(const bf16x8*)(fp + 512);
#pragma unroll
            for (int rh = 0; rh < 2; rh++)
#pragma unroll
                for (int ch = 0; ch < 2; ch++)
                    acc[di][rh][ch] = __builtin_amdgcn_mfma_f32_16x16x32_bf16(
                        (g & 1) ? fh[rh] : fa[rh], fb[ch], acc[di][rh][ch], 0, 0, 0);
        }
    }

    float b_r[2], b_z[2], b_in[2], b_hn[2];
#pragma unroll
    for (int ch = 0; ch < 2; ch++) {
        int jj = jw + ch * 16 + lr;
        b_r[ch]  = bih[jj] + bhh[jj];
        b_z[ch]  = bih[H + jj] + bhh[H + jj];
        b_in[ch] = bih[2 * H + jj];
        b_hn[ch] = bhh[2 * H + jj];
    }
#pragma unroll
    for (int rh = 0; rh < 2; rh++) {
#pragma unroll
        for (int reg = 0; reg < 4; reg++) {
            int row = rh * 16 + lg * 4 + reg;
            int n = n0 + row;
            if (n >= NN) continue;
#pragma unroll
            for (int ch = 0; ch < 2; ch++) {
                int jj = jw + ch * 16 + lr;
                float rr = acc[0][rh][ch][reg] + b_r[ch];
                float zz = acc[1][rh][ch][reg] + b_z[ch];
                float nn = acc[2][rh][ch][reg] + b_in[ch];
                float hn = acc[3][rh][ch][reg] + b_hn[ch];
                float r = frcp(1.f + fexp2(rr * -LOG2E));
                float z = frcp(1.f + fexp2(zz * -LOG2E));
                float x = nn + r * hn;
                float nv = 2.f * frcp(1.f + fexp2(x * -2.f * LOG2E)) - 1.f;
                float ho = bf2f((unsigned short)sH[row][jj]);
                float val = (1.f - z) * nv + z * ho;
                if (outf) outf[(size_t)n * H + jj] = val;
                else hnextb[(size_t)n * H + jj] = f2bf(val);
            }
        }
    }
}

extern "C" void kernel_launch(void* const* d_in, const int* in_sizes, int n_in,
                              void* d_out, int out_size, void* d_ws, size_t ws_size,
                              hipStream_t stream) {
    const int*   x     = (const int*)d_in[0];
    const int*   ei    = (const int*)d_in[1];
    const int*   etype = (const int*)d_in[2];
    const float* emb   = (const float*)d_in[3];
    const float* Wm    = (const float*)d_in[4];
    const float* bm    = (const float*)d_in[5];
    const float* wih   = (const float*)d_in[6];
    const float* whh   = (const float*)d_in[7];
    const float* bih   = (const float*)d_in[8];
    const float* bhh   = (const float*)d_in[9];

    float* out = (float*)d_out;

    // workspace layout
    short* hA    = (short*)d_ws;                         // [NN,H] bf16
    short* hB    = hA + (size_t)NN * H;                  // [NN,H] bf16
    short* wihp  = hB + (size_t)NN * H;                  // packed [3][8][16][64][8]
    short* whhp  = wihp + 3 * H * H;
    short* Wmp   = whhp + 3 * H * H;                     // packed [NT][8][16][64][8]
    short* msg   = Wmp + NT * H * H;                     // [NE,H] bf16
    int* hist_tb = (int*)(msg + (size_t)NE * H);         // [NT,NB]
    int* off_tb  = hist_tb + NT * NB;
    int* pstart  = off_tb + NT * NB;                     // [NT+1]
    int* perm    = pstart + 16;                          // [NE + NT*128]
    int* hist2   = perm + NE + NT * 128;                 // [NBIN,NB]
    int* off2    = hist2 + NBIN * NB;                    // [NBIN,NB]
    int* bintot  = off2 + NBIN * NB;                     // [NBIN]
    int* binstart= bintot + NBIN;                        // [NBIN+1]
    int* ebin    = binstart + NBIN + 1;                  // [NE]
    int* pos     = ebin + NE;                            // [NE]
    int* csr     = pos + NE;                             // [NN+1]

    k_embed<<<2048, 256, 0, stream>>>(x, emb, hA);
    k_prep<<<720, 256, 0, stream>>>(wih, whh, Wm, wihp, whhp, Wmp);

    // one-time: type sort (GEMM order)
    k_hist<<<NB, CHUNK, 0, stream>>>(etype, hist_tb);
    k_scan<<<1, 64, 0, stream>>>(hist_tb, off_tb, pstart, perm);
    k_scatter<<<NB, CHUNK, 0, stream>>>(etype, off_tb, pstart, perm);

    // one-time: dst sort (segment-sum order) -> pos[], csr[]
    k_hist2<<<NB, CHUNK, 0, stream>>>(ei, hist2);
    k_scan2a<<<(NBIN + 255) / 256, 256, 0, stream>>>(hist2, off2, bintot);
    k_scan2b<<<1, 1, 0, stream>>>(bintot, binstart, csr);
    k_scatter2<<<NB, CHUNK, 0, stream>>>(ei, off2, binstart, ebin);
    k_lsort<<<NBIN, 256, 0, stream>>>(ei, binstart, ebin, csr, pos);

    const int MSG_BX = (NE + NT * 128 + 127) / 128;
    const int GRU_BX = (NN + 31) / 32;     // 3125

    short* hcur = hA;
    short* hnxt = hB;
    for (int s = 0; s < NSTEPS; s++) {
        int last = (s == NSTEPS - 1);
        k_msg<<<MSG_BX, 512, 0, stream>>>(perm, pstart, ei, hcur, Wmp, bm, pos, msg);
        k_gru<<<GRU_BX, 512, 0, stream>>>(msg, csr, hcur, hnxt,
                                          last ? out : nullptr,
                                          wihp, whhp, bih, bhh);
        short* tmp = hcur; hcur = hnxt; hnxt = tmp;
    }
}